// Round 11
// baseline (169.267 us; speedup 1.0000x reference)
//
#include <hip/hip_runtime.h>
#include <hip/hip_bf16.h>

#define B_  8
#define T_  16
#define N_  1024
#define FI  32
#define FO  64
#define K_  3

typedef float  f32x4  __attribute__((ext_vector_type(4)));
typedef short  bf16x8 __attribute__((ext_vector_type(8)));
typedef unsigned int   u32x4 __attribute__((ext_vector_type(4)));

__device__ inline unsigned short f2bf(float f) {
    unsigned int u = __float_as_uint(f);
    u += 0x7fffu + ((u >> 16) & 1u);
    return (unsigned short)(u >> 16);
}

// packed fp32x2 -> bf16x2 (v_cvt_pk_bf16_f32 on gfx950)
__device__ inline unsigned int pkbf2(float a, float b) {
    __hip_bfloat162 h = __float22bfloat162_rn(make_float2(a, b));
    union { __hip_bfloat162 h2; unsigned int u; } cvt;
    cvt.h2 = h;
    return cvt.u;
}

// async 16-B global -> LDS (global_load_lds_dwordx4); LDS dest is
// wave-uniform base + lane*16 (contiguous per wave).
__device__ inline void gl_lds16(const unsigned short* g, unsigned short* l) {
    __builtin_amdgcn_global_load_lds(
        (const __attribute__((address_space(1))) unsigned int*)g,
        (__attribute__((address_space(3))) unsigned int*)l, 16, 0, 0);
}

// ---------------------------------------------------------------------------
// Kernel 1 "prep" (unchanged, proven):
//   tasks 0..2047   : transpose x[b,t,j,f] fp32 -> xt[b, t*32+f, j] bf16
//   tasks 2048..6143: AC[b,k,ij] = cheb[k,ij]*att[b,ij] bf16 (b-parallel)
// ---------------------------------------------------------------------------
__global__ __launch_bounds__(256)
void prep(const float* __restrict__ x, const float* __restrict__ att,
          const float* __restrict__ cheb,
          unsigned short* __restrict__ xt, unsigned short* __restrict__ ac) {
    __shared__ __align__(16) float tile[64][33];
    int task = blockIdx.x;
    int tid  = threadIdx.x;

    if (task < 2048) {
        int jt = task & 15;
        int bt = task >> 4;
        int j0 = jt * 64;
        const float* src = x + (size_t)bt * (N_ * FI) + (size_t)j0 * FI;
        #pragma unroll
        for (int s = 0; s < 2; s++) {
            int e4 = tid + s * 256;
            int j  = e4 >> 3;
            int f4 = e4 & 7;
            f32x4 v = *(const f32x4*)(src + j * FI + f4 * 4);
            tile[j][f4 * 4 + 0] = v[0];
            tile[j][f4 * 4 + 1] = v[1];
            tile[j][f4 * 4 + 2] = v[2];
            tile[j][f4 * 4 + 3] = v[3];
        }
        __syncthreads();
        int f  = tid >> 3;
        int j8 = (tid & 7) * 8;
        u32x4 pk;
        #pragma unroll
        for (int u = 0; u < 4; u++)
            pk[u] = pkbf2(tile[j8 + 2 * u][f], tile[j8 + 2 * u + 1][f]);
        *(u32x4*)(xt + (size_t)bt * (32 * 1024) + j0 + f * 1024 + j8) = pk;
    } else {
        int e  = (task - 2048) * 256 + tid;   // 0..1048575
        int b  = e >> 17;
        size_t ij = (size_t)(e & 131071) * 8;
        const float* ap = att + (size_t)b * (N_ * N_) + ij;
        f32x4 a0 = ((const f32x4*)ap)[0];
        f32x4 a1 = ((const f32x4*)ap)[1];
        #pragma unroll
        for (int k = 0; k < K_; k++) {
            const float* cp = cheb + (size_t)k * (N_ * N_) + ij;
            f32x4 c0 = ((const f32x4*)cp)[0];
            f32x4 c1 = ((const f32x4*)cp)[1];
            u32x4 pk;
            pk[0] = pkbf2(c0[0] * a0[0], c0[1] * a0[1]);
            pk[1] = pkbf2(c0[2] * a0[2], c0[3] * a0[3]);
            pk[2] = pkbf2(c1[0] * a1[0], c1[1] * a1[1]);
            pk[3] = pkbf2(c1[2] * a1[2], c1[3] * a1[3]);
            *(u32x4*)(ac + (size_t)(b * K_ + k) * (N_ * N_) + ij) = pk;
        }
    }
}

// ---------------------------------------------------------------------------
// Kernel 2 (fused, v10b = v10 with the Theta-staging trip-count bug fixed:
// 512 threads need 12 iterations to cover 6144 elements, not 3).
// OCCUPANCY VIA WAVE DECOMPOSITION: same 64i x 128c tile / grid 512 / BK=64
// / triple-buffer / counted-vmcnt schedule as v9 — but 512 threads (8
// waves): each wave owns 16i x 64c (acc[3][4]).  2 blocks/CU = 16 waves/CU
// = 4 waves/SIMD (2x v9's TLP), tile/traffic/ensembles UNCHANGED.
// A prefetch dropped (-48 VGPR) to fit 128-reg budget; KS order pinned
// ALOAD -> STAGE -> MFMA so the compiler's auto-wait for A (vmcnt<=2)
// leaves the new stage in flight AND implicitly drains the stage needed
// next KS.  WAR: buf(kb+2)%3 = buf(kb-1)%3, reads retired a KS ago.
// ---------------------------------------------------------------------------
#define TS_LD 104
#define CS_LD 104

__global__ __launch_bounds__(512, 4)
void fused_gemm(const unsigned short* __restrict__ ac,
                const unsigned short* __restrict__ xt,
                const float* __restrict__ theta,
                float* __restrict__ out) {
    // union: staging 3 x 8192 shorts (48 KB) lives under epilogue Cs
    // (4t x 64i x CS_LD = 26624 shorts = 53.2 KB).  + Ts 13.3 KB = 66.5 KB.
    __shared__ __align__(16) unsigned short ldsU[4 * 64 * CS_LD];
    __shared__ __align__(16) unsigned short Ts[FO * TS_LD];     // Theta^T

    unsigned short* Cs = ldsU;              // [4 t][64 i][CS_LD q]

    int blk  = blockIdx.x;
    int b    = blk & 7;          // XCD-aligned batch
    int slot = blk >> 3;         // 0..63
    int it   = slot >> 2;        // 0..15
    int ct   = slot & 3;         // 0..3
    int i0   = it * 64;
    int c0   = ct * 128;

    int tid  = threadIdx.x;      // 0..511
    int lane = tid & 63;
    int w    = tid >> 6;         // wave 0..7
    int wr   = w >> 1;           // i-quarter: rows wr*16..wr*16+15
    int wc   = w & 1;            // c-half: cols wc*64..wc*64+63
    int quad = lane >> 4;
    int l15  = lane & 15;

    // stage Theta^T: Ts[o][q] = bf16(theta[q*64+o]), q = k*32+f
    // 6144 elements / 512 threads = 12 iterations (v10's bug: had 3).
    #pragma unroll
    for (int s = 0; s < 12; s++) {
        int e = tid + s * 512;
        int q = e >> 6, o = e & 63;
        Ts[o * TS_LD + q] = f2bf(theta[e]);
    }
    // clean vmcnt slate before the counted region (theta loads were VMEM)
    asm volatile("s_waitcnt vmcnt(0)" ::: "memory");
    __builtin_amdgcn_sched_barrier(0);

    const unsigned short* Ag = ac + (size_t)b * (K_ * N_ * N_);
    const unsigned short* Bg = xt + (size_t)b * (512 * 1024);

    // ---- B staging (3-bit source swizzle, LDS linear; 2 gl_lds/thread) ----
    // seg0: rows 0..63 (row = tid>>3), seg1: rows 64..127.  sl = tid&7.
    // Source col slot = sl ^ (row&7); row&7 = (tid>>3)&7 for both segs.
    int srow = tid >> 3;                              // 0..63
    int scol = (((tid & 7) ^ (srow & 7)) * 8);        // swizzled source col
    const unsigned short* BrS0 = Bg + (size_t)(c0 + srow)      * N_ + scol;
    const unsigned short* BrS1 = Bg + (size_t)(c0 + srow + 64) * N_ + scol;
    unsigned short* R0 = ldsU;
    unsigned short* R1 = ldsU + 8192;
    unsigned short* R2 = ldsU + 16384;
    unsigned short* W0 = R0 + tid * 8;
    unsigned short* W1 = R1 + tid * 8;
    unsigned short* W2 = R2 + tid * 8;

    // read-side swizzle: logical slot s at LDS slot s ^ (row&7); the rows
    // this wave reads are wc*64 + nt*16 + l15 -> row&7 = l15&7.
    int sw  = l15 & 7;
    int rdB = (wc * 64 + l15) * 64;                   // + nt*16*64 per nt
    int rd0 = (quad ^ sw) * 8;                        // k-half 0: slots 0..3
    int rd1 = ((4 + quad) ^ sw) * 8;                  // k-half 1: slots 4..7

    // ---- A fragment pointers (direct global; row = i0 + wr*16 + l15) ----
    const unsigned short* Af0 = Ag + (size_t)(i0 + wr * 16 + l15) * N_ + quad * 8;
    const unsigned short* Af1 = Af0 + (size_t)N_ * N_;
    const unsigned short* Af2 = Af1 + (size_t)N_ * N_;

    f32x4 acc[3][4];
    #pragma unroll
    for (int k = 0; k < 3; k++)
        #pragma unroll
        for (int nt = 0; nt < 4; nt++)
            acc[k][nt] = (f32x4){0.f, 0.f, 0.f, 0.f};

#define STAGE(j, SW)                                                          \
    do {                                                                      \
        gl_lds16(BrS0 + (j) * 64, (SW));                                      \
        gl_lds16(BrS1 + (j) * 64, (SW) + 4096);                               \
    } while (0)

    // ---- prologue: stage0(2), stage1(2); drain stage0 (newer=2) ----
    STAGE(0, W0);
    __builtin_amdgcn_sched_barrier(0);
    STAGE(1, W1);
    asm volatile("s_waitcnt vmcnt(2)" ::: "memory");
    __builtin_amdgcn_s_barrier();
    __builtin_amdgcn_sched_barrier(0);

#define KS(kb, SR, SW, WN)                                                    \
  do {                                                                        \
    bf16x8 aC[3][2];                                                          \
    aC[0][0] = *(const bf16x8*)(Af0 + (kb) * 64);                             \
    aC[0][1] = *(const bf16x8*)(Af0 + (kb) * 64 + 32);                        \
    aC[1][0] = *(const bf16x8*)(Af1 + (kb) * 64);                             \
    aC[1][1] = *(const bf16x8*)(Af1 + (kb) * 64 + 32);                        \
    aC[2][0] = *(const bf16x8*)(Af2 + (kb) * 64);                             \
    aC[2][1] = *(const bf16x8*)(Af2 + (kb) * 64 + 32);                        \
    __builtin_amdgcn_sched_barrier(0);                                        \
    if ((kb) < 14) STAGE((kb) + 2, SW);                                       \
    __builtin_amdgcn_sched_barrier(0);                                        \
    __builtin_amdgcn_s_setprio(1);                                            \
    {                                                                         \
      bf16x8 b0[4];                                                           \
      _Pragma("unroll")                                                       \
      for (int nt = 0; nt < 4; nt++)                                          \
        b0[nt] = *(const bf16x8*)((SR) + rdB + nt * 1024 + rd0);              \
      _Pragma("unroll")                                                       \
      for (int nt = 0; nt < 4; nt++) {                                        \
        acc[0][nt] = __builtin_amdgcn_mfma_f32_16x16x32_bf16(aC[0][0], b0[nt], acc[0][nt], 0, 0, 0); \
        acc[1][nt] = __builtin_amdgcn_mfma_f32_16x16x32_bf16(aC[1][0], b0[nt], acc[1][nt], 0, 0, 0); \
        acc[2][nt] = __builtin_amdgcn_mfma_f32_16x16x32_bf16(aC[2][0], b0[nt], acc[2][nt], 0, 0, 0); \
      }                                                                       \
    }                                                                         \
    {                                                                         \
      bf16x8 b1[4];                                                           \
      _Pragma("unroll")                                                       \
      for (int nt = 0; nt < 4; nt++)                                          \
        b1[nt] = *(const bf16x8*)((SR) + rdB + nt * 1024 + rd1);              \
      _Pragma("unroll")                                                       \
      for (int nt = 0; nt < 4; nt++) {                                        \
        acc[0][nt] = __builtin_amdgcn_mfma_f32_16x16x32_bf16(aC[0][1], b1[nt], acc[0][nt], 0, 0, 0); \
        acc[1][nt] = __builtin_amdgcn_mfma_f32_16x16x32_bf16(aC[1][1], b1[nt], acc[1][nt], 0, 0, 0); \
        acc[2][nt] = __builtin_amdgcn_mfma_f32_16x16x32_bf16(aC[2][1], b1[nt], acc[2][nt], 0, 0, 0); \
      }                                                                       \
    }                                                                         \
    __builtin_amdgcn_s_setprio(0);                                            \
    asm volatile("s_waitcnt vmcnt(" WN ")" ::: "memory");                     \
    __builtin_amdgcn_s_barrier();                                             \
    __builtin_amdgcn_sched_barrier(0);                                        \
  } while (0)

    KS(0,  R0, W2, "2");
    KS(1,  R1, W0, "2");
    KS(2,  R2, W1, "2");
    KS(3,  R0, W2, "2");
    KS(4,  R1, W0, "2");
    KS(5,  R2, W1, "2");
    KS(6,  R0, W2, "2");
    KS(7,  R1, W0, "2");
    KS(8,  R2, W1, "2");
    KS(9,  R0, W2, "2");
    KS(10, R1, W0, "2");
    KS(11, R2, W1, "2");
    KS(12, R0, W2, "2");
    KS(13, R1, W0, "2");
    KS(14, R2, W0, "0");
    KS(15, R0, W0, "0");
#undef KS
#undef STAGE

    // ---- epilogue: acc -> bf16 Cs[t][i][q] ----
    // (last KS: vmcnt(0) drained all VMEM; ds_reads retired via MFMA
    //  consumption; final barrier synced -> Cs overlay safe)
    // C/D layout: col(c) = wc*64 + nt*16 + l15, row(i) = wr*16 + quad*4+reg
    // t_loc = wc*2 + (nt>>1), f = (nt&1)*16 + l15
    #pragma unroll
    for (int k = 0; k < 3; k++) {
        #pragma unroll
        for (int nt = 0; nt < 4; nt++) {
            int tl = wc * 2 + (nt >> 1);
            int q  = k * 32 + (nt & 1) * 16 + l15;
            #pragma unroll
            for (int reg = 0; reg < 4; reg++) {
                int il = wr * 16 + quad * 4 + reg;
                Cs[(tl * 64 + il) * CS_LD + q] = f2bf(acc[k][nt][reg]);
            }
        }
    }
    __syncthreads();

    // ---- second GEMM: out[i][o] = relu( Cs[t][i][q] * ThetaT[o][q] ) ----
    // wave w: tl = w>>1 (t-local), ih = (w&1)*32 (i-half), 2 mt x 16 rows.
    bf16x8 bq[4][3];
    #pragma unroll
    for (int nt2 = 0; nt2 < 4; nt2++)
        #pragma unroll
        for (int kc = 0; kc < 3; kc++)
            bq[nt2][kc] = *(const bf16x8*)(Ts + (nt2 * 16 + l15) * TS_LD + kc * 32 + quad * 8);

    {
        int tl = w >> 1;
        int ih = (w & 1) * 32;
        #pragma unroll
        for (int mt = 0; mt < 2; mt++) {
            bf16x8 af2[3];
            #pragma unroll
            for (int kc = 0; kc < 3; kc++)
                af2[kc] = *(const bf16x8*)(Cs +
                    (size_t)(tl * 64 + ih + mt * 16 + l15) * CS_LD + kc * 32 + quad * 8);
            f32x4 acc2[4];
            #pragma unroll
            for (int nt2 = 0; nt2 < 4; nt2++)
                acc2[nt2] = (f32x4){0.f, 0.f, 0.f, 0.f};
            #pragma unroll
            for (int kc = 0; kc < 3; kc++)
                #pragma unroll
                for (int nt2 = 0; nt2 < 4; nt2++)
                    acc2[nt2] = __builtin_amdgcn_mfma_f32_16x16x32_bf16(
                        af2[kc], bq[nt2][kc], acc2[nt2], 0, 0, 0);

            int tg = ct * 4 + tl;
            #pragma unroll
            for (int nt2 = 0; nt2 < 4; nt2++) {
                int o = nt2 * 16 + l15;
                #pragma unroll
                for (int reg = 0; reg < 4; reg++) {
                    size_t row = (size_t)(b * T_ + tg) * N_ +
                                 i0 + ih + mt * 16 + quad * 4 + reg;
                    out[row * 64 + o] = fmaxf(acc2[nt2][reg], 0.f);
                }
            }
        }
    }
}

// ---------------------------------------------------------------------------
extern "C" void kernel_launch(void* const* d_in, const int* in_sizes, int n_in,
                              void* d_out, int out_size, void* d_ws, size_t ws_size,
                              hipStream_t stream) {
    const float* x     = (const float*)d_in[0];   // [B,T,N,FI]
    const float* att   = (const float*)d_in[1];   // [B,N,N]
    const float* cheb  = (const float*)d_in[2];   // [K,N,N]
    const float* theta = (const float*)d_in[3];   // [K,FI,FO]
    float* out = (float*)d_out;                   // [B,T,N,FO]

    // workspace: xt bf16 8.4 MB | ac bf16 50.3 MB
    unsigned short* xt = (unsigned short*)d_ws;
    unsigned short* ac = xt + (size_t)B_ * 512 * 1024;

    prep<<<2048 + 4096, 256, 0, stream>>>(x, att, cheb, xt, ac);
    fused_gemm<<<512, 512, 0, stream>>>(ac, xt, theta, out);
}